// Round 1
// baseline (235.688 us; speedup 1.0000x reference)
//
#include <hip/hip_runtime.h>
#include <hip/hip_bf16.h>
#include <stdint.h>

// Problem: B=8, L=1024, C=1024, H=16, HD=64, window +/-64 (WS=128).
// Round-10: port both GEMMs from the 1-phase 128x128 structure (763 TF,
// MfmaUtil 30%, stall-bound on the per-K-step vmcnt drain) to the verified
// 256-wide 8-phase counted-vmcnt template (T3+T4+T5; T2 swizzle kept).
// qkv: 256x256 (384 blk); proj: 256x128 (256 blk = exactly 1/CU, fixes its
// 2-blk/CU occupancy). T1 chunked XCD swizzle on both. cast/attn unchanged.

typedef __attribute__((ext_vector_type(8))) short bf16x8;
typedef __attribute__((ext_vector_type(4))) float f32x4;

__device__ inline unsigned short f2b(float f) {
    __hip_bfloat16 h = __float2bfloat16(f);
    return *reinterpret_cast<unsigned short*>(&h);
}

// async global->LDS, 16B per lane; LDS dest = wave-uniform base + lane*16
__device__ inline void gld16(const unsigned short* g, unsigned short* l) {
    __builtin_amdgcn_global_load_lds(
        (const __attribute__((address_space(1))) void*)g,
        (__attribute__((address_space(3))) void*)l, 16, 0, 0);
}

// ---- cast f32 inputs to bf16 side buffers: 8 f32 -> one 16B store ----
__global__ void __launch_bounds__(256) cast_inputs(
    const float4* __restrict__ x, const float4* __restrict__ w1,
    const float4* __restrict__ w2,
    uint4* __restrict__ xb, uint4* __restrict__ w1b, uint4* __restrict__ w2b)
{
    const int P0 = 1048576, P1 = 393216, P2 = 131072;  // float4-pair counts
    int stride = gridDim.x * blockDim.x;
    for (int i = blockIdx.x * blockDim.x + threadIdx.x; i < P0 + P1 + P2; i += stride) {
        const float4* src; uint4* dst; int idx;
        if (i < P0)           { src = x;  dst = xb;  idx = i; }
        else if (i < P0 + P1) { src = w1; dst = w1b; idx = i - P0; }
        else                  { src = w2; dst = w2b; idx = i - P0 - P1; }
        float4 a = src[idx * 2], b = src[idx * 2 + 1];
        unsigned short t[8] = {f2b(a.x), f2b(a.y), f2b(a.z), f2b(a.w),
                               f2b(b.x), f2b(b.y), f2b(b.z), f2b(b.w)};
        dst[idx] = *(uint4*)t;
    }
}

// ================= 8-phase 256-row GEMM template =================
// C[M=8192, N] = A[M,1024] * W[N,1024]^T + bias.  BM=256, BK=64, 8 waves
// (wm=wave>>2 in {0,1}, wn=wave&3). INTERLEAVED frag map: m-frag f covers
// tile rows f*32+wm*16 (f=0..7: frags 0-3 in A-half0, 4-7 in A-half1);
// n-frag g covers tile cols g*64+wn*16 (g<NFN). So phase (qm,qn) reads ONLY
// A-half qm + B-half qn -> staged halves always have a full barrier-pair of
// separation from their last reader, making counted vmcnt legal.
//
// Per K-tile: 4 phases (qn-major: (0,0),(1,0),(0,1),(1,1)); per phase:
// ds_reads; stage 1 half; [vmcnt @ phase4 only]; bar; lgkmcnt(0); MFMAs; bar.
// Half-tile stage schedule (group t, buf P=t&1):
//   ph1: Ah1(t+1)->P^1   ph2: Bh1(t+1)->P^1
//   ph3: Bh0(t+2)->P     ph4: Ah0(t+2)->P, then vmcnt(4 qkv / 3 proj)
// Prologue: Ah0(0),Ah1(0),Bh0(0),Bh1(0),Bh0(1),Ah0(1); vmcnt leaves last 2
// halves floating. FIFO check: group-end vmcnt(4) always leaves exactly the
// two t+2 halves in flight; everything tile t+1 needs has landed.

#define STAGE_A(BUF, HM, T) do {                                              \
    const int rbA = (HM) * 128 + wave * 8;                                    \
    gld16(Aeff + (size_t)(rbA + drow) * 1024 + (T) * 64 + gcc * 8,            \
          &As[BUF][rbA * 64]);                                                \
    gld16(Aeff + (size_t)(rbA + 64 + drow) * 1024 + (T) * 64 + gcc * 8,       \
          &As[BUF][(rbA + 64) * 64]);                                         \
} while (0)

#define STAGE_B(BUF, HN, T) do {                                              \
    const int rbB = (HN) * (BN_T / 2) + wave * 8;                             \
    gld16(Weff + (size_t)(rbB + drow) * 1024 + (T) * 64 + gcc * 8,            \
          &Bs[BUF][rbB * 64]);                                                \
    if constexpr (BN_T == 256) {                                              \
        gld16(Weff + (size_t)(rbB + 64 + drow) * 1024 + (T) * 64 + gcc * 8,   \
              &Bs[BUF][(rbB + 64) * 64]);                                     \
    }                                                                         \
} while (0)

#define PH_READS(BUF, QM, QN) do {                                            \
    _Pragma("unroll")                                                         \
    for (int f = 0; f < 4; ++f) {                                             \
        const int ar = ((QM) * 128 + f * 32 + wm * 16 + lm) * 64;             \
        pa[f][0] = *(const bf16x8*)&As[BUF][ar + ((quad ^ lm7) << 3)];        \
        pa[f][1] = *(const bf16x8*)&As[BUF][ar + (((4 + quad) ^ lm7) << 3)];  \
    }                                                                         \
    _Pragma("unroll")                                                         \
    for (int g = 0; g < NGQ; ++g) {                                           \
        const int br = (((QN) * NGQ + g) * 64 + wn * 16 + lm) * 64;           \
        pb[g][0] = *(const bf16x8*)&Bs[BUF][br + ((quad ^ lm7) << 3)];        \
        pb[g][1] = *(const bf16x8*)&Bs[BUF][br + (((4 + quad) ^ lm7) << 3)];  \
    }                                                                         \
} while (0)

#define PH_MMA(QM, QN) do {                                                   \
    __builtin_amdgcn_s_barrier();                                             \
    asm volatile("s_waitcnt lgkmcnt(0)" ::: "memory");                        \
    __builtin_amdgcn_sched_barrier(0);                                        \
    __builtin_amdgcn_s_setprio(1);                                            \
    _Pragma("unroll")                                                         \
    for (int f = 0; f < 4; ++f) {                                             \
        _Pragma("unroll")                                                     \
        for (int g = 0; g < NGQ; ++g) {                                       \
            acc[(QM)*4+f][(QN)*NGQ+g] = __builtin_amdgcn_mfma_f32_16x16x32_bf16( \
                pa[f][0], pb[g][0], acc[(QM)*4+f][(QN)*NGQ+g], 0, 0, 0);      \
            acc[(QM)*4+f][(QN)*NGQ+g] = __builtin_amdgcn_mfma_f32_16x16x32_bf16( \
                pa[f][1], pb[g][1], acc[(QM)*4+f][(QN)*NGQ+g], 0, 0, 0);      \
        }                                                                     \
    }                                                                         \
    __builtin_amdgcn_s_setprio(0);                                            \
    __builtin_amdgcn_s_barrier();                                             \
} while (0)

#define VM_WAIT_STEADY do {                                                   \
    if constexpr (BN_T == 256) { asm volatile("s_waitcnt vmcnt(4)" ::: "memory"); } \
    else                       { asm volatile("s_waitcnt vmcnt(3)" ::: "memory"); } \
} while (0)

#define GROUP(BUF, T) do {                                                    \
    PH_READS(BUF, 0, 0); if ((T) + 1 < NT) STAGE_A((BUF)^1, 1, (T)+1); PH_MMA(0, 0); \
    PH_READS(BUF, 1, 0); if ((T) + 1 < NT) STAGE_B((BUF)^1, 1, (T)+1); PH_MMA(1, 0); \
    PH_READS(BUF, 0, 1); if ((T) + 2 < NT) STAGE_B(BUF, 0, (T)+2);     PH_MMA(0, 1); \
    PH_READS(BUF, 1, 1); if ((T) + 2 < NT) STAGE_A(BUF, 0, (T)+2);            \
    if ((T) + 2 < NT) { VM_WAIT_STEADY; }                                     \
    else { asm volatile("s_waitcnt vmcnt(0)" ::: "memory"); }                 \
    PH_MMA(1, 1);                                                             \
} while (0)

template<int BN_T, bool SCATTER>
__global__ void __launch_bounds__(512) gemm8p(
    const unsigned short* __restrict__ A,    // [8192,1024] bf16
    const unsigned short* __restrict__ W,    // [NDIM,1024] bf16
    const float* __restrict__ bias,          // [NDIM] f32
    unsigned short* __restrict__ Qo,
    unsigned short* __restrict__ Ko,
    unsigned short* __restrict__ Vo,
    float* __restrict__ Out)
{
    constexpr int NT  = 16;            // K tiles (K=1024 / BK=64)
    constexpr int NFN = BN_T / 64;     // n-frags per wave (4 or 2)
    constexpr int NGQ = NFN / 2;       // n-frags per phase (2 or 1)
    constexpr int NDIM = SCATTER ? 3072 : 1024;
    constexpr int NBX = NDIM / BN_T;   // 12 or 8
    constexpr int QC  = (NBX * 32) / 8;

    __shared__ unsigned short As[2][256 * 64];   // 64 KiB
    __shared__ unsigned short Bs[2][BN_T * 64];  // 64 / 32 KiB

    const int tid  = threadIdx.x;
    const int wave = tid >> 6, lane = tid & 63;
    const int wm = wave >> 2, wn = wave & 3;
    const int lm = lane & 15, quad = lane >> 4;
    const int lm7 = lm & 7;
    const int drow = lane >> 3;            // row within an 8-row DMA chunk
    const int gcc  = (lane & 7) ^ drow;    // inverse-swizzled global chunk

    // T1: chunked XCD swizzle (bijective: nwg % 8 == 0)
    const int id  = blockIdx.y * NBX + blockIdx.x;
    const int swz = (id & 7) * QC + (id >> 3);
    const int bx = swz % NBX, by = swz / NBX;
    const int m0 = by * 256, n0 = bx * BN_T;

    const unsigned short* Aeff = A + (size_t)m0 * 1024;
    const unsigned short* Weff = W + (size_t)n0 * 1024;

    f32x4 acc[8][NFN];
#pragma unroll
    for (int f = 0; f < 8; ++f)
#pragma unroll
        for (int g = 0; g < NFN; ++g)
            acc[f][g] = (f32x4){0.f, 0.f, 0.f, 0.f};

    bf16x8 pa[4][2];
    bf16x8 pb[NGQ][2];

    // prologue: tile0 fully + Bh0/Ah0 of tile1; drain tile0, float the rest
    STAGE_A(0, 0, 0);
    STAGE_A(0, 1, 0);
    STAGE_B(0, 0, 0);
    STAGE_B(0, 1, 0);
    STAGE_B(1, 0, 1);
    STAGE_A(1, 0, 1);
    VM_WAIT_STEADY;
    __builtin_amdgcn_s_barrier();

#pragma unroll 1
    for (int tp = 0; tp < NT / 2; ++tp) {
        const int te = 2 * tp;
        GROUP(0, te);
        GROUP(1, te + 1);
    }

    if constexpr (SCATTER) {
#pragma unroll
        for (int g = 0; g < NFN; ++g) {
            int n = n0 + g * 64 + wn * 16 + lm;
            float bv = bias[n];
            int sec = n >> 10, rem = n & 1023;
            int h = rem >> 6, d = rem & 63;
            unsigned short* dst = (sec == 0) ? Qo : (sec == 1) ? Ko : Vo;
#pragma unroll
            for (int f = 0; f < 8; ++f) {
#pragma unroll
                for (int r = 0; r < 4; ++r) {
                    int m = m0 + f * 32 + wm * 16 + quad * 4 + r;
                    int bb = m >> 10, sl = m & 1023;
                    size_t idx = ((size_t)((bb * 16 + h) * 1024 + sl)) * 64 + d;
                    dst[idx] = f2b(acc[f][g][r] + bv);
                }
            }
        }
    } else {
#pragma unroll
        for (int g = 0; g < NFN; ++g) {
            int n = n0 + g * 64 + wn * 16 + lm;
            float bv = bias[n];
#pragma unroll
            for (int f = 0; f < 8; ++f) {
#pragma unroll
                for (int r = 0; r < 4; ++r) {
                    int m = m0 + f * 32 + wm * 16 + quad * 4 + r;
                    Out[(size_t)m * 1024 + n] = acc[f][g][r] + bv;
                }
            }
        }
    }
}

// ---- local attention (unchanged, proven) ----
__global__ void __launch_bounds__(256) attn_local(
    const unsigned short* __restrict__ Qg,   // [B*H,1024,64] bf16
    const unsigned short* __restrict__ Kg,
    const unsigned short* __restrict__ Vg,
    unsigned short* __restrict__ Og)         // [8192,1024] bf16
{
    const int KP = 72;    // K-tile pitch (64+8)
    const int VP = 200;   // Vt / P pitch (192+8)
    __shared__ unsigned short Ks[192 * KP];  // reused as P after barrier
    __shared__ unsigned short Vt[64 * VP];

    int tid = threadIdx.x;
    int wave = tid >> 6, lane = tid & 63;
    int lm = lane & 15, quad = lane >> 4;

    int bh = blockIdx.x >> 4;
    int qt = blockIdx.x & 15;
    int q0 = qt * 64;
    int b = bh >> 4, h = bh & 15;
    const unsigned short* Qbh = Qg + (size_t)bh * 1024 * 64;
    const unsigned short* Kbh = Kg + (size_t)bh * 1024 * 64;
    const unsigned short* Vbh = Vg + (size_t)bh * 1024 * 64;
    int j0 = q0 - 64;

#pragma unroll
    for (int it = 0; it < 6; ++it) {
        int id = it * 256 + tid;
        int r = id >> 3;
        int c = (id & 7) * 8;
        int j = j0 + r;
        uint4 kv, vv;
        kv.x = kv.y = kv.z = kv.w = 0;
        vv = kv;
        if (j >= 0 && j < 1024) {
            kv = *(const uint4*)(Kbh + (size_t)j * 64 + c);
            vv = *(const uint4*)(Vbh + (size_t)j * 64 + c);
        }
        *(uint4*)(Ks + r * KP + c) = kv;
        unsigned short tmp[8];
        *(uint4*)tmp = vv;
#pragma unroll
        for (int e = 0; e < 8; ++e) Vt[(c + e) * VP + r] = tmp[e];
    }
    __syncthreads();

    int qrow = q0 + wave * 16;
    bf16x8 qf0 = *(const bf16x8*)(Qbh + (size_t)(qrow + lm) * 64 + quad * 8);
    bf16x8 qf1 = *(const bf16x8*)(Qbh + (size_t)(qrow + lm) * 64 + 32 + quad * 8);

    f32x4 sc[9];
#pragma unroll
    for (int kt = 0; kt < 9; ++kt) {
        int akt = wave + kt;
        f32x4 a = (f32x4){0.f, 0.f, 0.f, 0.f};
        bf16x8 k0f = *(const bf16x8*)(Ks + (akt * 16 + lm) * KP + quad * 8);
        bf16x8 k1f = *(const bf16x8*)(Ks + (akt * 16 + lm) * KP + 32 + quad * 8);
        a = __builtin_amdgcn_mfma_f32_16x16x32_bf16(qf0, k0f, a, 0, 0, 0);
        a = __builtin_amdgcn_mfma_f32_16x16x32_bf16(qf1, k1f, a, 0, 0, 0);
        sc[kt] = a;
    }

    float mx[4] = {-3e38f, -3e38f, -3e38f, -3e38f};
#pragma unroll
    for (int kt = 0; kt < 9; ++kt) {
        int jg = j0 + (wave + kt) * 16 + lm;
#pragma unroll
        for (int r = 0; r < 4; ++r) {
            int irow = q0 + wave * 16 + quad * 4 + r;
            int diff = irow - jg;
            bool ok = (jg >= 0) && (jg < 1024) && (diff <= 64) && (diff >= -64);
            float s = ok ? sc[kt][r] * 0.125f : -30000.0f;
            sc[kt][r] = s;
            mx[r] = fmaxf(mx[r], s);
        }
    }
#pragma unroll
    for (int off = 1; off <= 8; off <<= 1)
#pragma unroll
        for (int r = 0; r < 4; ++r)
            mx[r] = fmaxf(mx[r], __shfl_xor(mx[r], off, 64));

    float sum[4] = {0.f, 0.f, 0.f, 0.f};
#pragma unroll
    for (int kt = 0; kt < 9; ++kt)
#pragma unroll
        for (int r = 0; r < 4; ++r) {
            float p = __expf(sc[kt][r] - mx[r]);
            sc[kt][r] = p;
            sum[r] += p;
        }
#pragma unroll
    for (int off = 1; off <= 8; off <<= 1)
#pragma unroll
        for (int r = 0; r < 4; ++r)
            sum[r] += __shfl_xor(sum[r], off, 64);

    __syncthreads();
    unsigned short* Pb = Ks + wave * 3200;  // per-wave P [16][VP]
#pragma unroll
    for (int kt = 0; kt < 9; ++kt) {
        int akt = wave + kt;
#pragma unroll
        for (int r = 0; r < 4; ++r)
            Pb[(quad * 4 + r) * VP + akt * 16 + lm] = f2b(sc[kt][r]);
    }
    {
        int zkt = (wave & 1) ? (wave - 1) : (wave + 9);
#pragma unroll
        for (int r = 0; r < 4; ++r)
            Pb[(quad * 4 + r) * VP + zkt * 16 + lm] = 0;
    }
    __syncthreads();

    int jclo = wave >> 1;
    f32x4 o[4];
#pragma unroll
    for (int n = 0; n < 4; ++n) o[n] = (f32x4){0.f, 0.f, 0.f, 0.f};
#pragma unroll
    for (int jc2 = 0; jc2 < 5; ++jc2) {
        int jc = jclo + jc2;
        bf16x8 pf = *(const bf16x8*)(Pb + lm * VP + jc * 32 + quad * 8);
#pragma unroll
        for (int n = 0; n < 4; ++n) {
            bf16x8 vf = *(const bf16x8*)(Vt + (n * 16 + lm) * VP + jc * 32 + quad * 8);
            o[n] = __builtin_amdgcn_mfma_f32_16x16x32_bf16(pf, vf, o[n], 0, 0, 0);
        }
    }

    float inv[4];
#pragma unroll
    for (int r = 0; r < 4; ++r) inv[r] = 1.0f / sum[r];
#pragma unroll
    for (int n = 0; n < 4; ++n)
#pragma unroll
        for (int r = 0; r < 4; ++r) {
            int orow = q0 + wave * 16 + quad * 4 + r;
            size_t oidx = ((size_t)(b * 1024 + orow)) * 1024 + h * 64 + n * 16 + lm;
            Og[oidx] = f2b(o[n][r] * inv[r]);
        }
}

extern "C" void kernel_launch(void* const* d_in, const int* in_sizes, int n_in,
                              void* d_out, int out_size, void* d_ws, size_t ws_size,
                              hipStream_t stream) {
    const float* x  = (const float*)d_in[0];  // [8,1024,1024] f32
    const float* w1 = (const float*)d_in[1];  // [3072,1024] f32
    const float* b1 = (const float*)d_in[2];  // [3072] f32
    const float* w2 = (const float*)d_in[3];  // [1024,1024] f32
    const float* b2 = (const float*)d_in[4];  // [1024] f32
    float* out = (float*)d_out;               // [8192,1024] f32

    // ws (56 MiB peak):
    //  [0,16Mi)   xb  -> overlaid by attn after gemm_qkv
    //  [16,22Mi)  w1b -> dead after gemm_qkv
    //  [22,24Mi)  w2b
    //  [24,40Mi)  q   [40,56Mi) k
    //  v lives in d_out's first 16 MiB (dead before gemm_proj writes out)
    char* ws = (char*)d_ws;
    const size_t MB = 1024 * 1024;
    unsigned short* xb   = (unsigned short*)(ws);
    unsigned short* w1b  = (unsigned short*)(ws + 16 * MB);
    unsigned short* w2b  = (unsigned short*)(ws + 22 * MB);
    unsigned short* q    = (unsigned short*)(ws + 24 * MB);
    unsigned short* k    = (unsigned short*)(ws + 40 * MB);
    unsigned short* v    = (unsigned short*)d_out;
    unsigned short* attn = (unsigned short*)(ws);

    cast_inputs<<<1536, dim3(256), 0, stream>>>(
        (const float4*)x, (const float4*)w1, (const float4*)w2,
        (uint4*)xb, (uint4*)w1b, (uint4*)w2b);
    gemm8p<256, true><<<dim3(12, 32), dim3(512), 0, stream>>>(
        xb, w1b, b1, q, k, v, nullptr);
    attn_local<<<dim3(2048), dim3(256), 0, stream>>>(q, k, v, attn);
    gemm8p<128, false><<<dim3(8, 32), dim3(512), 0, stream>>>(
        attn, w2b, b2, nullptr, nullptr, nullptr, out);
}